// Round 17
// baseline (121.776 us; speedup 1.0000x reference)
//
#include <hip/hip_runtime.h>
#include <hip/hip_bf16.h>

// FiLM + 2-layer preact resnet. N=65536, H=256, C=512.
// Round 16 (resubmit after infra failure): K1 = r15 with ONE change:
// B-fragment prefetch distance raised from 1 ktl (~40cyc cover vs ~200cyc
// L2 latency -> ~150cyc exposed per ktl, the invariant across the
// r12/r14/r15 nulls) to a FULL CHUNK (4 ktl, ~640cyc cover): bbf[2][4][2]
// double buffer, chunk q+1's pair issued at chunk q's matching ktl (live
// frags flat at 10 = 40 VGPR). K2 unchanged.

typedef __attribute__((ext_vector_type(8))) short bf16x8;   // 8 bf16 = 4 VGPR
typedef __attribute__((ext_vector_type(4))) float f32x4;    // MFMA C/D

typedef unsigned short ushort_t;
typedef unsigned int uint_t;

__device__ __forceinline__ ushort_t f2bfh(float f) {
  __hip_bfloat16 h = __float2bfloat16(f);            // RNE, hw cvt
  return *reinterpret_cast<ushort_t*>(&h);
}
__device__ __forceinline__ float bf2f(ushort_t s) {
  union { uint_t u; float f; } v; v.u = ((uint_t)s) << 16;
  return v.f;
}
__device__ __forceinline__ bf16x8 ldfrag(const ushort_t* p) {
  return *reinterpret_cast<const bf16x8*>(p);
}
__device__ __forceinline__ bf16x8 pack8(float4 a, float4 b) {
  union { bf16x8 v; __hip_bfloat162 h[4]; } u;       // v_cvt_pk_bf16_f32 x4
  u.h[0] = __float22bfloat162_rn(float2{a.x, a.y});
  u.h[1] = __float22bfloat162_rn(float2{a.z, a.w});
  u.h[2] = __float22bfloat162_rn(float2{b.x, b.y});
  u.h[3] = __float22bfloat162_rn(float2{b.z, b.w});
  return u.v;
}

// ---------------------------------------------------------------------------
// Pack weights (fp32 row-major [K][Ncols]) into bf16 MFMA-B fragment order:
//   p[((nt*KT + kt)*64 + lane)*8 + j] = W[kt*32 + (lane>>4)*8 + j][nt*16 + (lane&15)]
// ---------------------------------------------------------------------------
__global__ void pack_weights(const float* __restrict__ Wf,
                             const float* __restrict__ W1,
                             const float* __restrict__ W2,
                             ushort_t* __restrict__ p1,
                             ushort_t* __restrict__ pW1,
                             ushort_t* __restrict__ pW2) {
  int u = blockIdx.x * 256 + threadIdx.x;
  if (u < 32768) {
    int lane = u & 63, rest = u >> 6;
    int kt = rest & 15;
    int kb = kt * 32 + (lane >> 4) * 8;
    int col = (rest >> 4) * 16 + (lane & 15);
#pragma unroll
    for (int j = 0; j < 8; ++j)
      p1[(size_t)u * 8 + j] = f2bfh(Wf[(size_t)(kb + j) * 512 + col]);
  } else if (u < 40960) {
    int v = u - 32768;
    int lane = v & 63;
    int kt = (v >> 6) & 7;
    int kb = kt * 32 + (lane >> 4) * 8;
    int col = (v >> 9) * 16 + (lane & 15);
#pragma unroll
    for (int j = 0; j < 8; ++j)
      pW1[(size_t)v * 8 + j] = f2bfh(W1[(size_t)(kb + j) * 256 + col]);
  } else if (u < 49152) {
    int v = u - 40960;
    int lane = v & 63;
    int kt = (v >> 6) & 7;
    int kb = kt * 32 + (lane >> 4) * 8;
    int col = (v >> 9) * 16 + (lane & 15);
#pragma unroll
    for (int j = 0; j < 8; ++j)
      pW2[(size_t)v * 8 + j] = f2bfh(W2[(size_t)(kb + j) * 256 + col]);
  }
}

// ---------------------------------------------------------------------------
// K1: blockIdx -> (rb = bid>>1 : 64 rows, ch = bid&1 : r1-cols [ch*128,+128)).
// 8 waves; wave w owns 16 r1-cols -> gamma panel ntg=ch*8+w, beta ntb=16+ch*8+w.
// LDS 48KB: c0/c1 cond chunk dbuf (bf16 [64][128] swz); xb x-half.
// Chunk q body: issue cond q+2, write q+1, {issue B-frag(q+1,ktl); MFMA q,ktl},
// barrier. B-frag cover = 1 full chunk. XOR swizzle: byte ^= (row&15)<<4.
// ---------------------------------------------------------------------------
__global__ __launch_bounds__(512, 2)
void k_gemm1_film(const float* __restrict__ x, const float* __restrict__ cond,
                  const float* __restrict__ b_film,
                  const ushort_t* __restrict__ p1,
                  ushort_t* __restrict__ r1g) {
  __shared__ __align__(16) char lds[49152];
  char* c0 = lds;
  char* c1 = lds + 16384;
  char* xb = lds + 32768;
  const int rb = blockIdx.x >> 1;
  const int ch = blockIdx.x & 1;
  const int r0 = rb * 64;
  const int t = threadIdx.x;
  const int w = t >> 6;          // 0..7
  const int l = t & 63;
  const int l15 = l & 15;
  const int lhi = l >> 4;

  const float bgv = b_film[ch * 128 + w * 16 + l15];
  const float bbv = b_film[256 + ch * 128 + w * 16 + l15];
  const int ntg = ch * 8 + w;
  const int ntb = 16 + ch * 8 + w;

  // ---- prologue: chunk 0 + x-half -> LDS; issue chunk 1 loads; preload
  // ALL 8 B-frags of chunk 0.
  float4 cA[4], cB[4];
  {
    float4 xv4[4];
#pragma unroll
    for (int p = 0; p < 2; ++p)
#pragma unroll
      for (int j = 0; j < 2; ++j) {
        int g = p * 1024 + t * 2 + j;
        int row = g >> 5, c4 = g & 31;
        cA[p * 2 + j] = *reinterpret_cast<const float4*>(
            cond + (size_t)(r0 + row) * 512 + c4 * 4);
        xv4[p * 2 + j] = *reinterpret_cast<const float4*>(
            x + (size_t)(r0 + row) * 256 + ch * 128 + c4 * 4);
      }
#pragma unroll
    for (int p = 0; p < 2; ++p) {
      int g = p * 1024 + t * 2;
      int row = g >> 5, c4 = g & 31;
      int byte = row * 256 + c4 * 8;
      byte ^= ((row & 15) << 4);
      *reinterpret_cast<bf16x8*>(c0 + byte) = pack8(cA[p * 2], cA[p * 2 + 1]);
      *reinterpret_cast<bf16x8*>(xb + byte) = pack8(xv4[p * 2], xv4[p * 2 + 1]);
    }
    // issue chunk 1 cond loads (stay in flight across the barrier)
#pragma unroll
    for (int p = 0; p < 2; ++p)
#pragma unroll
      for (int j = 0; j < 2; ++j) {
        int g = p * 1024 + t * 2 + j;
        int row = g >> 5, c4 = g & 31;
        cB[p * 2 + j] = *reinterpret_cast<const float4*>(
            cond + (size_t)(r0 + row) * 512 + 128 + c4 * 4);
      }
  }
  // full-chunk B-frag preload: chunk 0, all ktl
  bf16x8 bbf[2][4][2];
#pragma unroll
  for (int ktl = 0; ktl < 4; ++ktl) {
    bbf[0][ktl][0] = ldfrag(p1 + ((size_t)(ntg * 16 + ktl) * 64 + l) * 8);
    bbf[0][ktl][1] = ldfrag(p1 + ((size_t)(ntb * 16 + ktl) * 64 + l) * 8);
  }
  __syncthreads();   // chunk 0 + x staged

  f32x4 accg[4], accb[4];
#pragma unroll
  for (int m = 0; m < 4; ++m) {
    accg[m] = (f32x4){0.f, 0.f, 0.f, 0.f};
    accb[m] = (f32x4){0.f, 0.f, 0.f, 0.f};
  }

  // ---- main loop: chunk q = {issue cond q+2, write q+1,
  //                            [issue Bfrag(q+1,ktl); MFMA(q,ktl)]x4, barrier}
#pragma unroll
  for (int q = 0; q < 4; ++q) {
    const int cur = q & 1;
    // (a) issue chunk q+2 cond loads into the register set freed last chunk
    if (q < 2) {
      float4* dst = (q & 1) ? cB : cA;
#pragma unroll
      for (int p = 0; p < 2; ++p)
#pragma unroll
        for (int j = 0; j < 2; ++j) {
          int g = p * 1024 + t * 2 + j;
          int row = g >> 5, c4 = g & 31;
          dst[p * 2 + j] = *reinterpret_cast<const float4*>(
              cond + (size_t)(r0 + row) * 512 + (q + 2) * 128 + c4 * 4);
        }
    }
    // (b) cvt+write chunk q+1 -> its LDS buffer; readers finished at the
    //     previous barrier; the vmcnt wait overlaps the q+2 loads.
    if (q < 3) {
      const float4* src = (q & 1) ? cA : cB;
      char* wbuf = ((q + 1) & 1) ? c1 : c0;
#pragma unroll
      for (int p = 0; p < 2; ++p) {
        int g = p * 1024 + t * 2;
        int row = g >> 5, c4 = g & 31;
        int byte = row * 256 + c4 * 8;
        byte ^= ((row & 15) << 4);
        *reinterpret_cast<bf16x8*>(wbuf + byte) = pack8(src[p * 2], src[p * 2 + 1]);
      }
    }
    // (c) MFMA chunk q; at each ktl first issue chunk q+1's same-ktl B-frag
    //     pair (one-full-chunk prefetch distance, live frags flat at 10)
    const char* rbuf = (q & 1) ? c1 : c0;
#pragma unroll
    for (int ktl = 0; ktl < 4; ++ktl) {
      if (q < 3) {
        int ktn = (q + 1) * 4 + ktl;
        bbf[cur ^ 1][ktl][0] = ldfrag(p1 + ((size_t)(ntg * 16 + ktn) * 64 + l) * 8);
        bbf[cur ^ 1][ktl][1] = ldfrag(p1 + ((size_t)(ntb * 16 + ktn) * 64 + l) * 8);
      }
      __builtin_amdgcn_s_setprio(1);
#pragma unroll
      for (int m = 0; m < 4; ++m) {
        int row = m * 16 + l15;
        int byte = row * 256 + ktl * 64 + lhi * 16;
        byte ^= ((row & 15) << 4);
        bf16x8 a = *reinterpret_cast<const bf16x8*>(rbuf + byte);
        accg[m] = __builtin_amdgcn_mfma_f32_16x16x32_bf16(a, bbf[cur][ktl][0], accg[m], 0, 0, 0);
        accb[m] = __builtin_amdgcn_mfma_f32_16x16x32_bf16(a, bbf[cur][ktl][1], accb[m], 0, 0, 0);
      }
      __builtin_amdgcn_s_setprio(0);
    }
    // (d) one barrier per chunk
    __syncthreads();
  }

  // ---- FiLM -> bf16 r1 fragments into trbuf (=c0)
#pragma unroll
  for (int m = 0; m < 4; ++m) {
#pragma unroll
    for (int reg = 0; reg < 4; ++reg) {
      int row = m * 16 + lhi * 4 + reg;
      int colh = w * 16 + l15;
      int byte = row * 256 + colh * 2;
      byte ^= ((row & 15) << 4);
      float xv = bf2f(*reinterpret_cast<const ushort_t*>(xb + byte));
      float hv = fmaxf((accg[m][reg] + bgv) * xv + (accb[m][reg] + bbv), 0.f);
      *reinterpret_cast<ushort_t*>(c0 + byte) = f2bfh(hv);
    }
  }
  __syncthreads();   // trbuf complete

  // ---- coalesced r1 writeout ([64 rows][16 units of 16B])
#pragma unroll
  for (int it = 0; it < 2; ++it) {
    int u = it * 512 + t;
    int row = u >> 4, c16 = u & 15;
    int byte = row * 256 + c16 * 16;
    byte ^= ((row & 15) << 4);
    bf16x8 v = *reinterpret_cast<const bf16x8*>(c0 + byte);
    *reinterpret_cast<bf16x8*>(r1g + (size_t)(r0 + row) * 256 + ch * 128 + c16 * 8) = v;
  }
}

// ---------------------------------------------------------------------------
// K2: 1024 blocks x 64 rows, 8 waves; wave w owns out-cols [w*32,+32)
// (nt = w*2+tt). LDS 32KB region R: r1 bf16 [64][256] swz -> r2 in place ->
// epilogue fp32 [32][256] halves. XOR swizzle byte ^= (row&15)<<4.
// ---------------------------------------------------------------------------
__global__ __launch_bounds__(512, 2)
void k_mlp(const ushort_t* __restrict__ r1g, const float* __restrict__ x,
           const float* __restrict__ b1, const float* __restrict__ b2,
           const ushort_t* __restrict__ pW1, const ushort_t* __restrict__ pW2,
           float* __restrict__ out) {
  __shared__ __align__(16) char R[32768];
  const int r0 = blockIdx.x * 64;
  const int t = threadIdx.x;
  const int w = t >> 6;
  const int l = t & 63;
  const int l15 = l & 15;
  const int lhi = l >> 4;

  float b1v[2], b2v[2];
#pragma unroll
  for (int tt = 0; tt < 2; ++tt) {
    int col = w * 32 + tt * 16 + l15;
    b1v[tt] = b1[col];
    b2v[tt] = b2[col];
  }

  // ---- stage r1 tile (bf16, 16B/lane coalesced)
#pragma unroll
  for (int it = 0; it < 4; ++it) {
    int u = it * 512 + t;
    int row = u >> 5, c8 = u & 31;
    bf16x8 v = *reinterpret_cast<const bf16x8*>(r1g + (size_t)(r0 + row) * 256 + c8 * 8);
    int byte = row * 512 + c8 * 16;
    byte ^= ((row & 15) << 4);
    *reinterpret_cast<bf16x8*>(R + byte) = v;
  }
  bf16x8 bb2[2][2];
#pragma unroll
  for (int tt = 0; tt < 2; ++tt)
    bb2[0][tt] = ldfrag(pW1 + ((size_t)((w * 2 + tt) * 8 + 0) * 64 + l) * 8);
  __syncthreads();   // r1 staged

  // ---- GEMM2
  f32x4 acc2[4][2];
#pragma unroll
  for (int m = 0; m < 4; ++m)
#pragma unroll
    for (int n = 0; n < 2; ++n) acc2[m][n] = (f32x4){0.f, 0.f, 0.f, 0.f};

#pragma unroll
  for (int kt = 0; kt < 8; ++kt) {
    const int cur = kt & 1;
    if (kt < 7) {
#pragma unroll
      for (int tt = 0; tt < 2; ++tt)
        bb2[cur ^ 1][tt] = ldfrag(pW1 + ((size_t)((w * 2 + tt) * 8 + kt + 1) * 64 + l) * 8);
    }
    bf16x8 afr[4];
#pragma unroll
    for (int m = 0; m < 4; ++m) {
      int row = m * 16 + l15;
      int byte = row * 512 + kt * 64 + lhi * 16;
      byte ^= ((row & 15) << 4);
      afr[m] = *reinterpret_cast<const bf16x8*>(R + byte);
    }
    __builtin_amdgcn_s_setprio(1);
#pragma unroll
    for (int tt = 0; tt < 2; ++tt)
#pragma unroll
      for (int m = 0; m < 4; ++m)
        acc2[m][tt] = __builtin_amdgcn_mfma_f32_16x16x32_bf16(afr[m], bb2[cur][tt], acc2[m][tt], 0, 0, 0);
    __builtin_amdgcn_s_setprio(0);
  }
  __syncthreads();   // all r1 reads done -> in-place r2 safe

  // ---- r2 = relu(acc2+b1) in place; preload GEMM3 frags
  bf16x8 bb3[2][2];
#pragma unroll
  for (int tt = 0; tt < 2; ++tt)
    bb3[0][tt] = ldfrag(pW2 + ((size_t)((w * 2 + tt) * 8 + 0) * 64 + l) * 8);
#pragma unroll
  for (int tt = 0; tt < 2; ++tt) {
    int col = w * 32 + tt * 16 + l15;
#pragma unroll
    for (int m = 0; m < 4; ++m) {
#pragma unroll
      for (int reg = 0; reg < 4; ++reg) {
        int row = m * 16 + lhi * 4 + reg;
        int byte = row * 512 + col * 2;
        byte ^= ((row & 15) << 4);
        *reinterpret_cast<ushort_t*>(R + byte) = f2bfh(fmaxf(acc2[m][tt][reg] + b1v[tt], 0.f));
      }
    }
  }
  __syncthreads();   // r2 ready

  // ---- GEMM3
  f32x4 acc3[4][2];
#pragma unroll
  for (int m = 0; m < 4; ++m)
#pragma unroll
    for (int n = 0; n < 2; ++n) acc3[m][n] = (f32x4){0.f, 0.f, 0.f, 0.f};

#pragma unroll
  for (int kt = 0; kt < 8; ++kt) {
    const int cur = kt & 1;
    if (kt < 7) {
#pragma unroll
      for (int tt = 0; tt < 2; ++tt)
        bb3[cur ^ 1][tt] = ldfrag(pW2 + ((size_t)((w * 2 + tt) * 8 + kt + 1) * 64 + l) * 8);
    }
    bf16x8 afr[4];
#pragma unroll
    for (int m = 0; m < 4; ++m) {
      int row = m * 16 + l15;
      int byte = row * 512 + kt * 64 + lhi * 16;
      byte ^= ((row & 15) << 4);
      afr[m] = *reinterpret_cast<const bf16x8*>(R + byte);
    }
    __builtin_amdgcn_s_setprio(1);
#pragma unroll
    for (int tt = 0; tt < 2; ++tt)
#pragma unroll
      for (int m = 0; m < 4; ++m)
        acc3[m][tt] = __builtin_amdgcn_mfma_f32_16x16x32_bf16(afr[m], bb3[cur][tt], acc3[m][tt], 0, 0, 0);
    __builtin_amdgcn_s_setprio(0);
  }
  __syncthreads();   // all r2 reads done -> R free

  // ---- epilogue: two 32-row halves; +b2 at dump, +x at coalesced store
#pragma unroll
  for (int hh = 0; hh < 2; ++hh) {
    if (hh) __syncthreads();   // half-0 store reads done
#pragma unroll
    for (int tt = 0; tt < 2; ++tt) {
      int col = w * 32 + tt * 16 + l15;
#pragma unroll
      for (int mm = 0; mm < 2; ++mm) {
        int m = hh * 2 + mm;
#pragma unroll
        for (int reg = 0; reg < 4; ++reg) {
          int r = mm * 16 + lhi * 4 + reg;
          int byte = r * 1024 + col * 4;
          byte ^= ((r & 15) << 4);
          *reinterpret_cast<float*>(R + byte) = acc3[m][tt][reg] + b2v[tt];
        }
      }
    }
    __syncthreads();
#pragma unroll
    for (int i = 0; i < 4; ++i) {
      int u = i * 512 + t;
      int r = u >> 6, c4 = u & 63;   // [32 rows][64 units of 4 cols]
      int byte = r * 1024 + c4 * 16;
      byte ^= ((r & 15) << 4);
      f32x4 v = *reinterpret_cast<const f32x4*>(R + byte);
      int grow = hh * 32 + r;
      const float4 xres = *reinterpret_cast<const float4*>(
          x + (size_t)(r0 + grow) * 256 + c4 * 4);
      v.x += xres.x; v.y += xres.y; v.z += xres.z; v.w += xres.w;
      f32x4* op = reinterpret_cast<f32x4*>(out + (size_t)(r0 + grow) * 256 + c4 * 4);
      __builtin_nontemporal_store(v, op);
    }
  }
}

extern "C" void kernel_launch(void* const* d_in, const int* in_sizes, int n_in,
                              void* d_out, int out_size, void* d_ws, size_t ws_size,
                              hipStream_t stream) {
  const float* x      = (const float*)d_in[0];
  const float* cond   = (const float*)d_in[1];
  const float* W_film = (const float*)d_in[2];
  const float* b_film = (const float*)d_in[3];
  const float* W1     = (const float*)d_in[4];
  const float* b1     = (const float*)d_in[5];
  const float* W2     = (const float*)d_in[6];
  const float* b2     = (const float*)d_in[7];
  float* out = (float*)d_out;

  ushort_t* p1  = (ushort_t*)d_ws;       // 512KB
  ushort_t* pW1 = p1 + 262144;           // 128KB
  ushort_t* pW2 = pW1 + 65536;           // 128KB
  ushort_t* r1g = pW2 + 65536;           // 65536*256 bf16 = 32MB

  hipLaunchKernelGGL(pack_weights, dim3(192), dim3(256), 0, stream,
                     W_film, W1, W2, p1, pW1, pW2);
  hipLaunchKernelGGL(k_gemm1_film, dim3(2048), dim3(512), 0, stream,
                     x, cond, b_film, p1, r1g);
  hipLaunchKernelGGL(k_mlp, dim3(1024), dim3(512), 0, stream,
                     r1g, x, b1, b2, pW1, pW2, out);
}

// Round 18
// 98.263 us; speedup vs baseline: 1.2393x; 1.2393x over previous
//
#include <hip/hip_runtime.h>
#include <hip/hip_bf16.h>

// FiLM + 2-layer preact resnet. N=65536, H=256, C=512.
// Round 18: FUSED kernel, gamma/beta exchanged through LDS.
// GEMM1: wave w owns 64 contiguous gb cols (waves 0-3 gamma, 4-7 beta) ->
// acc[4][4]=64 VGPR (not 128). gb(+b_film) dumped bf16 to LDS [64][512];
// FiLM reads gamma/beta from LDS row-major (x coalesced from global), writes
// r1 IN PLACE over the gamma half; GEMM2 reads gamma-half, r2 -> beta half,
// GEMM3 reads it; fp32-LDS epilogue with L3-warm x re-read (r12-K2 pattern).
// Peak live ~116 < (512,2)'s 128-box -> no spill, 2 blocks/CU, no r1
// round-trip, cond read once. Kills r10's 244-VGPR 1-block/CU limiter.

typedef __attribute__((ext_vector_type(8))) short bf16x8;   // 8 bf16 = 4 VGPR
typedef __attribute__((ext_vector_type(4))) float f32x4;    // MFMA C/D

typedef unsigned short ushort_t;
typedef unsigned int uint_t;

__device__ __forceinline__ ushort_t f2bfh(float f) {
  __hip_bfloat16 h = __float2bfloat16(f);            // RNE, hw cvt
  return *reinterpret_cast<ushort_t*>(&h);
}
__device__ __forceinline__ float bf2f(ushort_t s) {
  union { uint_t u; float f; } v; v.u = ((uint_t)s) << 16;
  return v.f;
}
__device__ __forceinline__ bf16x8 ldfrag(const ushort_t* p) {
  return *reinterpret_cast<const bf16x8*>(p);
}
__device__ __forceinline__ bf16x8 pack8(float4 a, float4 b) {
  union { bf16x8 v; __hip_bfloat162 h[4]; } u;       // v_cvt_pk_bf16_f32 x4
  u.h[0] = __float22bfloat162_rn(float2{a.x, a.y});
  u.h[1] = __float22bfloat162_rn(float2{a.z, a.w});
  u.h[2] = __float22bfloat162_rn(float2{b.x, b.y});
  u.h[3] = __float22bfloat162_rn(float2{b.z, b.w});
  return u.v;
}

// ---------------------------------------------------------------------------
// Pack weights (fp32 row-major [K][Ncols]) into bf16 MFMA-B fragment order:
//   p[((nt*KT + kt)*64 + lane)*8 + j] = W[kt*32 + (lane>>4)*8 + j][nt*16 + (lane&15)]
// ---------------------------------------------------------------------------
__global__ void pack_weights(const float* __restrict__ Wf,
                             const float* __restrict__ W1,
                             const float* __restrict__ W2,
                             ushort_t* __restrict__ p1,
                             ushort_t* __restrict__ pW1,
                             ushort_t* __restrict__ pW2) {
  int u = blockIdx.x * 256 + threadIdx.x;
  if (u < 32768) {
    int lane = u & 63, rest = u >> 6;
    int kt = rest & 15;
    int kb = kt * 32 + (lane >> 4) * 8;
    int col = (rest >> 4) * 16 + (lane & 15);
#pragma unroll
    for (int j = 0; j < 8; ++j)
      p1[(size_t)u * 8 + j] = f2bfh(Wf[(size_t)(kb + j) * 512 + col]);
  } else if (u < 40960) {
    int v = u - 32768;
    int lane = v & 63;
    int kt = (v >> 6) & 7;
    int kb = kt * 32 + (lane >> 4) * 8;
    int col = (v >> 9) * 16 + (lane & 15);
#pragma unroll
    for (int j = 0; j < 8; ++j)
      pW1[(size_t)v * 8 + j] = f2bfh(W1[(size_t)(kb + j) * 256 + col]);
  } else if (u < 49152) {
    int v = u - 40960;
    int lane = v & 63;
    int kt = (v >> 6) & 7;
    int kb = kt * 32 + (lane >> 4) * 8;
    int col = (v >> 9) * 16 + (lane & 15);
#pragma unroll
    for (int j = 0; j < 8; ++j)
      pW2[(size_t)v * 8 + j] = f2bfh(W2[(size_t)(kb + j) * 256 + col]);
  }
}

// ---------------------------------------------------------------------------
// Fused: 1024 blocks x 64 rows, 8 waves (512 thr).
// LDS 64KB [64][512] bf16 (1KB/row), XOR swz byte ^= (row&15)<<4:
//   phase 1: cond (full K)
//   phase 2: gb bf16 (gamma cols 0-255, beta cols 256-511)
//   phase 3: r1 over gamma-half (stride 1KB), r2 over beta-half
//   phase 4: fp32 out tile [32][256] per half in lds[0,32K)
// GEMM1: wave w owns gb cols [w*64,+64) -> acc[4][4]. GEMM2/3: wave w owns
// H-cols [w*32,+32) -> acc[4][2].
// ---------------------------------------------------------------------------
__global__ __launch_bounds__(512, 2)
void film_fused(const float* __restrict__ x, const float* __restrict__ cond,
                const float* __restrict__ b_film, const float* __restrict__ b1,
                const float* __restrict__ b2,
                const ushort_t* __restrict__ p1, const ushort_t* __restrict__ pW1,
                const ushort_t* __restrict__ pW2, float* __restrict__ out) {
  __shared__ __align__(16) char lds[65536];
  const int r0 = blockIdx.x * 64;
  const int t = threadIdx.x;
  const int w = t >> 6;
  const int l = t & 63;
  const int l15 = l & 15;
  const int lhi = l >> 4;

  // bias preloads: GEMM1 dump cols (w*64..+64 of gb), GEMM2/3 cols (w*32..)
  float bfv[4], b1v[2], b2v[2];
#pragma unroll
  for (int tt = 0; tt < 4; ++tt) bfv[tt] = b_film[w * 64 + tt * 16 + l15];
#pragma unroll
  for (int tt = 0; tt < 2; ++tt) {
    int col = w * 32 + tt * 16 + l15;
    b1v[tt] = b1[col];
    b2v[tt] = b2[col];
  }

  // ---- stage cond full-K -> bf16 LDS [64][512] swz
#pragma unroll
  for (int it = 0; it < 8; ++it) {
    int u = it * 512 + t;
    int row = u >> 6, k8 = u & 63;
    const float4* cs = reinterpret_cast<const float4*>(cond + (size_t)(r0 + row) * 512 + k8 * 8);
    float4 a = cs[0], b = cs[1];
    int byte = row * 1024 + k8 * 16;
    byte ^= ((row & 15) << 4);
    *reinterpret_cast<bf16x8*>(lds + byte) = pack8(a, b);
  }
  // GEMM1 B preload kt=0 (4 panels: nt = w*4+tt covers all 32 gb n-tiles)
  bf16x8 bb[2][4];
#pragma unroll
  for (int tt = 0; tt < 4; ++tt)
    bb[0][tt] = ldfrag(p1 + ((size_t)((w * 4 + tt) * 16 + 0) * 64 + l) * 8);
  __syncthreads();   // B1: cond staged

  // ---- GEMM1: acc[4][4] over 16 kt, 2-slot B pipeline
  f32x4 acc[4][4];
#pragma unroll
  for (int m = 0; m < 4; ++m)
#pragma unroll
    for (int n = 0; n < 4; ++n) acc[m][n] = (f32x4){0.f, 0.f, 0.f, 0.f};

#pragma unroll
  for (int kt = 0; kt < 16; ++kt) {
    const int cur = kt & 1;
    if (kt < 15) {
#pragma unroll
      for (int tt = 0; tt < 4; ++tt)
        bb[cur ^ 1][tt] = ldfrag(p1 + ((size_t)((w * 4 + tt) * 16 + kt + 1) * 64 + l) * 8);
    }
    bf16x8 afr[4];
#pragma unroll
    for (int m = 0; m < 4; ++m) {
      int row = m * 16 + l15;
      int byte = row * 1024 + kt * 64 + lhi * 16;
      byte ^= ((row & 15) << 4);
      afr[m] = *reinterpret_cast<const bf16x8*>(lds + byte);
    }
    __builtin_amdgcn_s_setprio(1);
#pragma unroll
    for (int tt = 0; tt < 4; ++tt)
#pragma unroll
      for (int m = 0; m < 4; ++m)
        acc[m][tt] = __builtin_amdgcn_mfma_f32_16x16x32_bf16(afr[m], bb[cur][tt], acc[m][tt], 0, 0, 0);
    __builtin_amdgcn_s_setprio(0);
  }
  __syncthreads();   // B2: all cond reads done -> LDS reusable

  // ---- dump gb(+b_film) bf16 -> LDS [64][512] (wave w covers cols w*64..+64)
#pragma unroll
  for (int tt = 0; tt < 4; ++tt) {
    int col = w * 64 + tt * 16 + l15;
#pragma unroll
    for (int m = 0; m < 4; ++m) {
#pragma unroll
      for (int reg = 0; reg < 4; ++reg) {
        int row = m * 16 + lhi * 4 + reg;
        int byte = row * 1024 + col * 2;
        byte ^= ((row & 15) << 4);
        *reinterpret_cast<ushort_t*>(lds + byte) = f2bfh(acc[m][tt][reg] + bfv[tt]);
      }
    }
  }
  // GEMM2 B preload before the barrier
  bf16x8 bb2[2][2];
#pragma unroll
  for (int tt = 0; tt < 2; ++tt)
    bb2[0][tt] = ldfrag(pW1 + ((size_t)((w * 2 + tt) * 8 + 0) * 64 + l) * 8);
  __syncthreads();   // B3: gb ready

  // ---- FiLM row-major: r1 = relu(gamma*x + beta) written IN PLACE over the
  // gamma half. Each (row, 8-col unit) slot read+written by exactly one thread.
#pragma unroll
  for (int i = 0; i < 4; ++i) {
    int u = i * 512 + t;
    int row = u >> 5, c8 = u & 31;        // [64 rows][32 units of 8 gamma-cols]
    int gbyte = row * 1024 + c8 * 16;
    gbyte ^= ((row & 15) << 4);
    int bbyte = row * 1024 + 512 + c8 * 16;
    bbyte ^= ((row & 15) << 4);
    union { bf16x8 v; ushort_t s[8]; } g, be, r;
    g.v = *reinterpret_cast<const bf16x8*>(lds + gbyte);
    be.v = *reinterpret_cast<const bf16x8*>(lds + bbyte);
    const float4* xs = reinterpret_cast<const float4*>(x + (size_t)(r0 + row) * 256 + c8 * 8);
    float4 xa = xs[0], xb = xs[1];
    float xv[8] = {xa.x, xa.y, xa.z, xa.w, xb.x, xb.y, xb.z, xb.w};
#pragma unroll
    for (int j = 0; j < 8; ++j)
      r.s[j] = f2bfh(fmaxf(bf2f(g.s[j]) * xv[j] + bf2f(be.s[j]), 0.f));
    *reinterpret_cast<bf16x8*>(lds + gbyte) = r.v;
  }
  __syncthreads();   // B4: r1 ready (gamma half)

  // ---- GEMM2: acc2 = r1 @ W1 (K=256, 8 kt; A stride 1KB, gamma half)
  f32x4 acc2[4][2];
#pragma unroll
  for (int m = 0; m < 4; ++m)
#pragma unroll
    for (int n = 0; n < 2; ++n) acc2[m][n] = (f32x4){0.f, 0.f, 0.f, 0.f};

#pragma unroll
  for (int kt = 0; kt < 8; ++kt) {
    const int cur = kt & 1;
    if (kt < 7) {
#pragma unroll
      for (int tt = 0; tt < 2; ++tt)
        bb2[cur ^ 1][tt] = ldfrag(pW1 + ((size_t)((w * 2 + tt) * 8 + kt + 1) * 64 + l) * 8);
    }
    bf16x8 afr[4];
#pragma unroll
    for (int m = 0; m < 4; ++m) {
      int row = m * 16 + l15;
      int byte = row * 1024 + kt * 64 + lhi * 16;
      byte ^= ((row & 15) << 4);
      afr[m] = *reinterpret_cast<const bf16x8*>(lds + byte);
    }
    __builtin_amdgcn_s_setprio(1);
#pragma unroll
    for (int tt = 0; tt < 2; ++tt)
#pragma unroll
      for (int m = 0; m < 4; ++m)
        acc2[m][tt] = __builtin_amdgcn_mfma_f32_16x16x32_bf16(afr[m], bb2[cur][tt], acc2[m][tt], 0, 0, 0);
    __builtin_amdgcn_s_setprio(0);
  }

  // ---- r2 = relu(acc2+b1) -> BETA half (disjoint from GEMM2's gamma-half
  // reads -> no barrier needed before these writes). GEMM3 B preload too.
  bf16x8 bb3[2][2];
#pragma unroll
  for (int tt = 0; tt < 2; ++tt)
    bb3[0][tt] = ldfrag(pW2 + ((size_t)((w * 2 + tt) * 8 + 0) * 64 + l) * 8);
#pragma unroll
  for (int tt = 0; tt < 2; ++tt) {
    int col = w * 32 + tt * 16 + l15;
#pragma unroll
    for (int m = 0; m < 4; ++m) {
#pragma unroll
      for (int reg = 0; reg < 4; ++reg) {
        int row = m * 16 + lhi * 4 + reg;
        int byte = row * 1024 + 512 + col * 2;
        byte ^= ((row & 15) << 4);
        *reinterpret_cast<ushort_t*>(lds + byte) = f2bfh(fmaxf(acc2[m][tt][reg] + b1v[tt], 0.f));
      }
    }
  }
  __syncthreads();   // B5: r2 ready (beta half)

  // ---- GEMM3: acc3 = r2 @ W2 (A stride 1KB, beta half)
  f32x4 acc3[4][2];
#pragma unroll
  for (int m = 0; m < 4; ++m)
#pragma unroll
    for (int n = 0; n < 2; ++n) acc3[m][n] = (f32x4){0.f, 0.f, 0.f, 0.f};

#pragma unroll
  for (int kt = 0; kt < 8; ++kt) {
    const int cur = kt & 1;
    if (kt < 7) {
#pragma unroll
      for (int tt = 0; tt < 2; ++tt)
        bb3[cur ^ 1][tt] = ldfrag(pW2 + ((size_t)((w * 2 + tt) * 8 + kt + 1) * 64 + l) * 8);
    }
    bf16x8 afr[4];
#pragma unroll
    for (int m = 0; m < 4; ++m) {
      int row = m * 16 + l15;
      int byte = row * 1024 + 512 + kt * 64 + lhi * 16;
      byte ^= ((row & 15) << 4);
      afr[m] = *reinterpret_cast<const bf16x8*>(lds + byte);
    }
    __builtin_amdgcn_s_setprio(1);
#pragma unroll
    for (int tt = 0; tt < 2; ++tt)
#pragma unroll
      for (int m = 0; m < 4; ++m)
        acc3[m][tt] = __builtin_amdgcn_mfma_f32_16x16x32_bf16(afr[m], bb3[cur][tt], acc3[m][tt], 0, 0, 0);
    __builtin_amdgcn_s_setprio(0);
  }
  __syncthreads();   // B6: all r2 reads done -> whole LDS free

  // ---- epilogue: two 32-row halves through lds[0,32K) (fp32 [32][256] swz),
  // +b2 at dump, +x (L3-warm re-read) at coalesced nontemporal store.
#pragma unroll
  for (int hh = 0; hh < 2; ++hh) {
    if (hh) __syncthreads();   // half-0 store reads done
#pragma unroll
    for (int tt = 0; tt < 2; ++tt) {
      int col = w * 32 + tt * 16 + l15;
#pragma unroll
      for (int mm = 0; mm < 2; ++mm) {
        int m = hh * 2 + mm;
#pragma unroll
        for (int reg = 0; reg < 4; ++reg) {
          int r = mm * 16 + lhi * 4 + reg;
          int byte = r * 1024 + col * 4;
          byte ^= ((r & 15) << 4);
          *reinterpret_cast<float*>(lds + byte) = acc3[m][tt][reg] + b2v[tt];
        }
      }
    }
    __syncthreads();
#pragma unroll
    for (int i = 0; i < 4; ++i) {
      int u = i * 512 + t;
      int r = u >> 6, c4 = u & 63;   // [32 rows][64 units of 4 cols]
      int byte = r * 1024 + c4 * 16;
      byte ^= ((r & 15) << 4);
      f32x4 v = *reinterpret_cast<const f32x4*>(lds + byte);
      int grow = hh * 32 + r;
      const float4 xres = *reinterpret_cast<const float4*>(
          x + (size_t)(r0 + grow) * 256 + c4 * 4);
      v.x += xres.x; v.y += xres.y; v.z += xres.z; v.w += xres.w;
      f32x4* op = reinterpret_cast<f32x4*>(out + (size_t)(r0 + grow) * 256 + c4 * 4);
      __builtin_nontemporal_store(v, op);
    }
  }
}

extern "C" void kernel_launch(void* const* d_in, const int* in_sizes, int n_in,
                              void* d_out, int out_size, void* d_ws, size_t ws_size,
                              hipStream_t stream) {
  const float* x      = (const float*)d_in[0];
  const float* cond   = (const float*)d_in[1];
  const float* W_film = (const float*)d_in[2];
  const float* b_film = (const float*)d_in[3];
  const float* W1     = (const float*)d_in[4];
  const float* b1     = (const float*)d_in[5];
  const float* W2     = (const float*)d_in[6];
  const float* b2     = (const float*)d_in[7];
  float* out = (float*)d_out;

  ushort_t* p1  = (ushort_t*)d_ws;       // 512KB
  ushort_t* pW1 = p1 + 262144;           // 128KB
  ushort_t* pW2 = pW1 + 65536;           // 128KB

  hipLaunchKernelGGL(pack_weights, dim3(192), dim3(256), 0, stream,
                     W_film, W1, W2, p1, pW1, pW2);
  hipLaunchKernelGGL(film_fused, dim3(1024), dim3(512), 0, stream,
                     x, cond, b_film, b1, b2, p1, pW1, pW2, out);
}

// Round 19
// 97.545 us; speedup vs baseline: 1.2484x; 1.0074x over previous
//
#include <hip/hip_runtime.h>
#include <hip/hip_bf16.h>

// FiLM + 2-layer preact resnet. N=65536, H=256, C=512.
// Round 19: r18 fused structure + chunked cond staging via global_load_lds
// (async DMA, pre-swizzled global source, linear LDS dest): 8 chunks of
// [64][64] fp32 (16KB) through 4 rotating buffers; chunk c+2 issued at the
// top of chunk c's MFMA body -> each barrier drain covered by MFMA, and the
// two resident blocks interleave HBM/MFMA at ~300cyc grain instead of
// phase-locking. A-frags read fp32 + cvt_pk (same RNE values as r18).
// Post-GEMM1 (gb dump / FiLM / GEMM2/3 / epilogue) identical to r18.

typedef __attribute__((ext_vector_type(8))) short bf16x8;   // 8 bf16 = 4 VGPR
typedef __attribute__((ext_vector_type(4))) float f32x4;    // MFMA C/D

typedef unsigned short ushort_t;
typedef unsigned int uint_t;

__device__ __forceinline__ ushort_t f2bfh(float f) {
  __hip_bfloat16 h = __float2bfloat16(f);            // RNE, hw cvt
  return *reinterpret_cast<ushort_t*>(&h);
}
__device__ __forceinline__ float bf2f(ushort_t s) {
  union { uint_t u; float f; } v; v.u = ((uint_t)s) << 16;
  return v.f;
}
__device__ __forceinline__ bf16x8 ldfrag(const ushort_t* p) {
  return *reinterpret_cast<const bf16x8*>(p);
}
__device__ __forceinline__ bf16x8 pack8(float4 a, float4 b) {
  union { bf16x8 v; __hip_bfloat162 h[4]; } u;       // v_cvt_pk_bf16_f32 x4
  u.h[0] = __float22bfloat162_rn(float2{a.x, a.y});
  u.h[1] = __float22bfloat162_rn(float2{a.z, a.w});
  u.h[2] = __float22bfloat162_rn(float2{b.x, b.y});
  u.h[3] = __float22bfloat162_rn(float2{b.z, b.w});
  return u.v;
}
__device__ __forceinline__ bf16x8 pack8v(f32x4 a, f32x4 b) {
  union { bf16x8 v; __hip_bfloat162 h[4]; } u;
  u.h[0] = __float22bfloat162_rn(float2{a[0], a[1]});
  u.h[1] = __float22bfloat162_rn(float2{a[2], a[3]});
  u.h[2] = __float22bfloat162_rn(float2{b[0], b[1]});
  u.h[3] = __float22bfloat162_rn(float2{b[2], b[3]});
  return u.v;
}

// ---------------------------------------------------------------------------
// Pack weights (fp32 row-major [K][Ncols]) into bf16 MFMA-B fragment order:
//   p[((nt*KT + kt)*64 + lane)*8 + j] = W[kt*32 + (lane>>4)*8 + j][nt*16 + (lane&15)]
// ---------------------------------------------------------------------------
__global__ void pack_weights(const float* __restrict__ Wf,
                             const float* __restrict__ W1,
                             const float* __restrict__ W2,
                             ushort_t* __restrict__ p1,
                             ushort_t* __restrict__ pW1,
                             ushort_t* __restrict__ pW2) {
  int u = blockIdx.x * 256 + threadIdx.x;
  if (u < 32768) {
    int lane = u & 63, rest = u >> 6;
    int kt = rest & 15;
    int kb = kt * 32 + (lane >> 4) * 8;
    int col = (rest >> 4) * 16 + (lane & 15);
#pragma unroll
    for (int j = 0; j < 8; ++j)
      p1[(size_t)u * 8 + j] = f2bfh(Wf[(size_t)(kb + j) * 512 + col]);
  } else if (u < 40960) {
    int v = u - 32768;
    int lane = v & 63;
    int kt = (v >> 6) & 7;
    int kb = kt * 32 + (lane >> 4) * 8;
    int col = (v >> 9) * 16 + (lane & 15);
#pragma unroll
    for (int j = 0; j < 8; ++j)
      pW1[(size_t)v * 8 + j] = f2bfh(W1[(size_t)(kb + j) * 256 + col]);
  } else if (u < 49152) {
    int v = u - 40960;
    int lane = v & 63;
    int kt = (v >> 6) & 7;
    int kb = kt * 32 + (lane >> 4) * 8;
    int col = (v >> 9) * 16 + (lane & 15);
#pragma unroll
    for (int j = 0; j < 8; ++j)
      pW2[(size_t)v * 8 + j] = f2bfh(W2[(size_t)(kb + j) * 256 + col]);
  }
}

// ---------------------------------------------------------------------------
// Fused: 1024 blocks x 64 rows, 8 waves (512 thr). LDS 64KB.
// GEMM1 phase: 4 x 16KB chunk buffers (fp32 [64][64], linear dest,
//   source-pre-swizzled slot' = slot ^ (row&15), 16B slots, 16 slots/row).
// Post-GEMM1: gb bf16 [64][512] (1KB/row, byte ^= (row&15)<<4), then r1 over
//   gamma half, r2 over beta half, fp32 epilogue tile — identical to r18.
// ---------------------------------------------------------------------------
__global__ __launch_bounds__(512, 2)
void film_fused(const float* __restrict__ x, const float* __restrict__ cond,
                const float* __restrict__ b_film, const float* __restrict__ b1,
                const float* __restrict__ b2,
                const ushort_t* __restrict__ p1, const ushort_t* __restrict__ pW1,
                const ushort_t* __restrict__ pW2, float* __restrict__ out) {
  __shared__ __align__(16) char lds[65536];
  const int r0 = blockIdx.x * 64;
  const int t = threadIdx.x;
  const int w = t >> 6;
  const int l = t & 63;
  const int l15 = l & 15;
  const int lhi = l >> 4;

  // bias preloads
  float bfv[4], b1v[2], b2v[2];
#pragma unroll
  for (int tt = 0; tt < 4; ++tt) bfv[tt] = b_film[w * 64 + tt * 16 + l15];
#pragma unroll
  for (int tt = 0; tt < 2; ++tt) {
    int col = w * 32 + tt * 16 + l15;
    b1v[tt] = b1[col];
    b2v[tt] = b2[col];
  }

  // ---- chunked async staging: chunk c (64 cols fp32) -> buffer (c&3).
  // Per thread 2 gll of 16B: u = i*512+t; row=u>>4; slot=u&15;
  // global col-byte = c*256 + ((slot ^ (row&15))<<4).
  const char* condb = reinterpret_cast<const char*>(cond);
#define STAGE_CHUNK(c)                                                        \
  {                                                                           \
    char* qb = lds + ((c) & 3) * 16384;                                       \
    _Pragma("unroll")                                                         \
    for (int i = 0; i < 2; ++i) {                                             \
      int u = i * 512 + t;                                                    \
      int row = u >> 4, slot = u & 15;                                        \
      const char* g = condb + (size_t)(r0 + row) * 2048 + (c) * 256 +         \
                      ((slot ^ (row & 15)) << 4);                             \
      __builtin_amdgcn_global_load_lds(                                       \
          (const __attribute__((address_space(1))) void*)g,                   \
          (__attribute__((address_space(3))) void*)(qb + u * 16), 16, 0, 0);  \
    }                                                                         \
  }

  // prologue: chunks 0,1 in flight; B-frag kt=0 preload
  STAGE_CHUNK(0)
  STAGE_CHUNK(1)
  bf16x8 bb[2][4];
#pragma unroll
  for (int tt = 0; tt < 4; ++tt)
    bb[0][tt] = ldfrag(p1 + ((size_t)((w * 4 + tt) * 16 + 0) * 64 + l) * 8);
  __syncthreads();   // chunks 0,1 landed

  // ---- GEMM1: acc[4][4]; 8 chunks x 2 kt; B 2-slot 1-kt lead
  f32x4 acc[4][4];
#pragma unroll
  for (int m = 0; m < 4; ++m)
#pragma unroll
    for (int n = 0; n < 4; ++n) acc[m][n] = (f32x4){0.f, 0.f, 0.f, 0.f};

#pragma unroll
  for (int c = 0; c < 8; ++c) {
    if (c < 6) STAGE_CHUNK(c + 2)            // issued early; drained at (d)
    const char* qb = lds + (c & 3) * 16384;
#pragma unroll
    for (int ktl = 0; ktl < 2; ++ktl) {
      const int kt = c * 2 + ktl;
      const int cur = kt & 1;
      if (kt < 15) {
#pragma unroll
        for (int tt = 0; tt < 4; ++tt)
          bb[cur ^ 1][tt] = ldfrag(p1 + ((size_t)((w * 4 + tt) * 16 + kt + 1) * 64 + l) * 8);
      }
      bf16x8 afr[4];
#pragma unroll
      for (int m = 0; m < 4; ++m) {
        int row = m * 16 + l15;
        int sw = row & 15;
        int s0 = ktl * 8 + lhi * 2;
        f32x4 f0 = *reinterpret_cast<const f32x4*>(qb + row * 256 + ((s0 ^ sw) << 4));
        f32x4 f1 = *reinterpret_cast<const f32x4*>(qb + row * 256 + (((s0 + 1) ^ sw) << 4));
        afr[m] = pack8v(f0, f1);
      }
      __builtin_amdgcn_s_setprio(1);
#pragma unroll
      for (int tt = 0; tt < 4; ++tt)
#pragma unroll
        for (int m = 0; m < 4; ++m)
          acc[m][tt] = __builtin_amdgcn_mfma_f32_16x16x32_bf16(afr[m], bb[cur][tt], acc[m][tt], 0, 0, 0);
      __builtin_amdgcn_s_setprio(0);
    }
    __syncthreads();   // (d) chunk c reads done; chunk c+2 landed
  }
  // all chunk buffers dead -> whole LDS free for gb

  // ---- dump gb(+b_film) bf16 -> LDS [64][512] (wave w covers cols w*64..+64)
#pragma unroll
  for (int tt = 0; tt < 4; ++tt) {
    int col = w * 64 + tt * 16 + l15;
#pragma unroll
    for (int m = 0; m < 4; ++m) {
#pragma unroll
      for (int reg = 0; reg < 4; ++reg) {
        int row = m * 16 + lhi * 4 + reg;
        int byte = row * 1024 + col * 2;
        byte ^= ((row & 15) << 4);
        *reinterpret_cast<ushort_t*>(lds + byte) = f2bfh(acc[m][tt][reg] + bfv[tt]);
      }
    }
  }
  // GEMM2 B preload before the barrier
  bf16x8 bb2[2][2];
#pragma unroll
  for (int tt = 0; tt < 2; ++tt)
    bb2[0][tt] = ldfrag(pW1 + ((size_t)((w * 2 + tt) * 8 + 0) * 64 + l) * 8);
  __syncthreads();   // gb ready

  // ---- FiLM row-major: r1 = relu(gamma*x + beta) IN PLACE over gamma half
#pragma unroll
  for (int i = 0; i < 4; ++i) {
    int u = i * 512 + t;
    int row = u >> 5, c8 = u & 31;
    int gbyte = row * 1024 + c8 * 16;
    gbyte ^= ((row & 15) << 4);
    int bbyte = row * 1024 + 512 + c8 * 16;
    bbyte ^= ((row & 15) << 4);
    union { bf16x8 v; ushort_t s[8]; } g, be, r;
    g.v = *reinterpret_cast<const bf16x8*>(lds + gbyte);
    be.v = *reinterpret_cast<const bf16x8*>(lds + bbyte);
    const float4* xs = reinterpret_cast<const float4*>(x + (size_t)(r0 + row) * 256 + c8 * 8);
    float4 xa = xs[0], xb = xs[1];
    float xv[8] = {xa.x, xa.y, xa.z, xa.w, xb.x, xb.y, xb.z, xb.w};
#pragma unroll
    for (int j = 0; j < 8; ++j)
      r.s[j] = f2bfh(fmaxf(bf2f(g.s[j]) * xv[j] + bf2f(be.s[j]), 0.f));
    *reinterpret_cast<bf16x8*>(lds + gbyte) = r.v;
  }
  __syncthreads();   // r1 ready (gamma half)

  // ---- GEMM2: acc2 = r1 @ W1 (K=256, 8 kt; A stride 1KB, gamma half)
  f32x4 acc2[4][2];
#pragma unroll
  for (int m = 0; m < 4; ++m)
#pragma unroll
    for (int n = 0; n < 2; ++n) acc2[m][n] = (f32x4){0.f, 0.f, 0.f, 0.f};

#pragma unroll
  for (int kt = 0; kt < 8; ++kt) {
    const int cur = kt & 1;
    if (kt < 7) {
#pragma unroll
      for (int tt = 0; tt < 2; ++tt)
        bb2[cur ^ 1][tt] = ldfrag(pW1 + ((size_t)((w * 2 + tt) * 8 + kt + 1) * 64 + l) * 8);
    }
    bf16x8 afr[4];
#pragma unroll
    for (int m = 0; m < 4; ++m) {
      int row = m * 16 + l15;
      int byte = row * 1024 + kt * 64 + lhi * 16;
      byte ^= ((row & 15) << 4);
      afr[m] = *reinterpret_cast<const bf16x8*>(lds + byte);
    }
    __builtin_amdgcn_s_setprio(1);
#pragma unroll
    for (int tt = 0; tt < 2; ++tt)
#pragma unroll
      for (int m = 0; m < 4; ++m)
        acc2[m][tt] = __builtin_amdgcn_mfma_f32_16x16x32_bf16(afr[m], bb2[cur][tt], acc2[m][tt], 0, 0, 0);
    __builtin_amdgcn_s_setprio(0);
  }

  // ---- r2 = relu(acc2+b1) -> beta half (disjoint from GEMM2 reads)
  bf16x8 bb3[2][2];
#pragma unroll
  for (int tt = 0; tt < 2; ++tt)
    bb3[0][tt] = ldfrag(pW2 + ((size_t)((w * 2 + tt) * 8 + 0) * 64 + l) * 8);
#pragma unroll
  for (int tt = 0; tt < 2; ++tt) {
    int col = w * 32 + tt * 16 + l15;
#pragma unroll
    for (int m = 0; m < 4; ++m) {
#pragma unroll
      for (int reg = 0; reg < 4; ++reg) {
        int row = m * 16 + lhi * 4 + reg;
        int byte = row * 1024 + 512 + col * 2;
        byte ^= ((row & 15) << 4);
        *reinterpret_cast<ushort_t*>(lds + byte) = f2bfh(fmaxf(acc2[m][tt][reg] + b1v[tt], 0.f));
      }
    }
  }
  __syncthreads();   // r2 ready (beta half)

  // ---- GEMM3: acc3 = r2 @ W2 (A stride 1KB, beta half)
  f32x4 acc3[4][2];
#pragma unroll
  for (int m = 0; m < 4; ++m)
#pragma unroll
    for (int n = 0; n < 2; ++n) acc3[m][n] = (f32x4){0.f, 0.f, 0.f, 0.f};

#pragma unroll
  for (int kt = 0; kt < 8; ++kt) {
    const int cur = kt & 1;
    if (kt < 7) {
#pragma unroll
      for (int tt = 0; tt < 2; ++tt)
        bb3[cur ^ 1][tt] = ldfrag(pW2 + ((size_t)((w * 2 + tt) * 8 + kt + 1) * 64 + l) * 8);
    }
    bf16x8 afr[4];
#pragma unroll
    for (int m = 0; m < 4; ++m) {
      int row = m * 16 + l15;
      int byte = row * 1024 + 512 + kt * 64 + lhi * 16;
      byte ^= ((row & 15) << 4);
      afr[m] = *reinterpret_cast<const bf16x8*>(lds + byte);
    }
    __builtin_amdgcn_s_setprio(1);
#pragma unroll
    for (int tt = 0; tt < 2; ++tt)
#pragma unroll
      for (int m = 0; m < 4; ++m)
        acc3[m][tt] = __builtin_amdgcn_mfma_f32_16x16x32_bf16(afr[m], bb3[cur][tt], acc3[m][tt], 0, 0, 0);
    __builtin_amdgcn_s_setprio(0);
  }
  __syncthreads();   // all r2 reads done -> whole LDS free

  // ---- epilogue: two 32-row halves through lds[0,32K) (fp32 [32][256] swz),
  // +b2 at dump, +x (L3-warm re-read) at coalesced nontemporal store.
#pragma unroll
  for (int hh = 0; hh < 2; ++hh) {
    if (hh) __syncthreads();
#pragma unroll
    for (int tt = 0; tt < 2; ++tt) {
      int col = w * 32 + tt * 16 + l15;
#pragma unroll
      for (int mm = 0; mm < 2; ++mm) {
        int m = hh * 2 + mm;
#pragma unroll
        for (int reg = 0; reg < 4; ++reg) {
          int r = mm * 16 + lhi * 4 + reg;
          int byte = r * 1024 + col * 4;
          byte ^= ((r & 15) << 4);
          *reinterpret_cast<float*>(lds + byte) = acc3[m][tt][reg] + b2v[tt];
        }
      }
    }
    __syncthreads();
#pragma unroll
    for (int i = 0; i < 4; ++i) {
      int u = i * 512 + t;
      int r = u >> 6, c4 = u & 63;
      int byte = r * 1024 + c4 * 16;
      byte ^= ((r & 15) << 4);
      f32x4 v = *reinterpret_cast<const f32x4*>(lds + byte);
      int grow = hh * 32 + r;
      const float4 xres = *reinterpret_cast<const float4*>(
          x + (size_t)(r0 + grow) * 256 + c4 * 4);
      v.x += xres.x; v.y += xres.y; v.z += xres.z; v.w += xres.w;
      f32x4* op = reinterpret_cast<f32x4*>(out + (size_t)(r0 + grow) * 256 + c4 * 4);
      __builtin_nontemporal_store(v, op);
    }
  }
#undef STAGE_CHUNK
}

extern "C" void kernel_launch(void* const* d_in, const int* in_sizes, int n_in,
                              void* d_out, int out_size, void* d_ws, size_t ws_size,
                              hipStream_t stream) {
  const float* x      = (const float*)d_in[0];
  const float* cond   = (const float*)d_in[1];
  const float* W_film = (const float*)d_in[2];
  const float* b_film = (const float*)d_in[3];
  const float* W1     = (const float*)d_in[4];
  const float* b1     = (const float*)d_in[5];
  const float* W2     = (const float*)d_in[6];
  const float* b2     = (const float*)d_in[7];
  float* out = (float*)d_out;

  ushort_t* p1  = (ushort_t*)d_ws;       // 512KB
  ushort_t* pW1 = p1 + 262144;           // 128KB
  ushort_t* pW2 = pW1 + 65536;           // 128KB

  hipLaunchKernelGGL(pack_weights, dim3(192), dim3(256), 0, stream,
                     W_film, W1, W2, p1, pW1, pW2);
  hipLaunchKernelGGL(film_fused, dim3(1024), dim3(512), 0, stream,
                     x, cond, b_film, b1, b2, p1, pW1, pW2, out);
}